// Round 17
// baseline (242.954 us; speedup 1.0000x reference)
//
#include <hip/hip_runtime.h>
#include <stdint.h>

#define BKT 1024   // nodes per coarse bucket
#define EPB 4096   // edges per partition block

typedef __attribute__((ext_vector_type(8))) __bf16 bf16x8;
typedef __attribute__((ext_vector_type(4))) float floatx4;

// ---- bf16 helpers (RNE pack, exact expand) ----
__device__ __forceinline__ float bf2f(unsigned short h) {
    return __uint_as_float(((unsigned)h) << 16);
}
__device__ __forceinline__ float4 bf4(ushort4 v) {
    return make_float4(bf2f(v.x), bf2f(v.y), bf2f(v.z), bf2f(v.w));
}
__device__ __forceinline__ unsigned short f2bf(float f) {
    unsigned u = __float_as_uint(f);
    u = u + 0x7FFFu + ((u >> 16) & 1u);
    return (unsigned short)(u >> 16);
}
__device__ __forceinline__ unsigned packpair(float lo, float hi) {
    return ((unsigned)f2bf(lo)) | ((unsigned)f2bf(hi) << 16);
}

// =============== coarse histogram ===============

__global__ __launch_bounds__(256) void coarse_hist(const int* __restrict__ dst,
                                                   int* __restrict__ coarse, int E, int NBK) {
    __shared__ int h[128];
    if (threadIdx.x < 128) h[threadIdx.x] = 0;
    __syncthreads();
    int stride = gridDim.x * 256;
    int gid = blockIdx.x * 256 + threadIdx.x;
    const int4* d4 = (const int4*)dst;
    int E4 = E >> 2;
    for (int i = gid; i < E4; i += stride) {
        int4 v = d4[i];
        atomicAdd(&h[v.x >> 10], 1);
        atomicAdd(&h[v.y >> 10], 1);
        atomicAdd(&h[v.z >> 10], 1);
        atomicAdd(&h[v.w >> 10], 1);
    }
    for (int i = (E4 << 2) + gid; i < E; i += stride)
        atomicAdd(&h[dst[i] >> 10], 1);
    __syncthreads();
    if (threadIdx.x < NBK) {
        int v = h[threadIdx.x];
        if (v) atomicAdd(&coarse[threadIdx.x], v);
    }
}

// coarse_scan + w3l fused: thread 0 scans, all 64 compute w3l[k]
__global__ void scan_w3l_kernel(const int* __restrict__ coarse, int* __restrict__ bbase,
                                const float* __restrict__ W3, const float* __restrict__ Wl,
                                float* __restrict__ w3l, int NBK, int E) {
    int k = threadIdx.x;   // 64 threads
    float s = 0.f;
#pragma unroll 16
    for (int c = 0; c < 64; ++c) s += W3[k * 64 + c] * Wl[c];
    w3l[k] = s;
    if (k == 0) {
        int run = 0;
        for (int i = 0; i < NBK; ++i) { bbase[i] = run; run += coarse[i]; }
        bbase[NBK] = E;
    }
}

// =============== Phase A: counting-sort partition; packed u32 pairs ===============
// pair = (src << 10) | (dst & 1023)

__global__ __launch_bounds__(256) void partition_kernel(const int* __restrict__ src,
                                                        const int* __restrict__ dst,
                                                        const int* __restrict__ bbase,
                                                        int* __restrict__ gbcur,
                                                        unsigned* __restrict__ pairs,
                                                        int E, int NBK) {
    __shared__ unsigned stage[EPB];      // 16 KB
    __shared__ int hist[128], offs[129], gbase[128], lcur[128];
    int base = blockIdx.x * EPB;
    int cntE = min(EPB, E - base);
    if (threadIdx.x < 128) hist[threadIdx.x] = 0;
    __syncthreads();
    {
        const int4* d4 = (const int4*)(dst + base);   // base is EPB-aligned
        int c4 = cntE >> 2;
        for (int i = threadIdx.x; i < c4; i += 256) {
            int4 v = d4[i];
            atomicAdd(&hist[v.x >> 10], 1);
            atomicAdd(&hist[v.y >> 10], 1);
            atomicAdd(&hist[v.z >> 10], 1);
            atomicAdd(&hist[v.w >> 10], 1);
        }
        for (int i = (c4 << 2) + (int)threadIdx.x; i < cntE; i += 256)
            atomicAdd(&hist[dst[base + i] >> 10], 1);
    }
    __syncthreads();
    if (threadIdx.x == 0) {
        int run = 0;
        for (int b = 0; b < NBK; ++b) { offs[b] = run; run += hist[b]; }
        offs[NBK] = run;
    }
    __syncthreads();
    if (threadIdx.x < NBK) {
        int b = threadIdx.x;
        int h = hist[b];
        if (h > 0) gbase[b] = bbase[b] + atomicAdd(&gbcur[b << 4], h);
        lcur[b] = offs[b];
    }
    __syncthreads();
    for (int i = threadIdx.x; i < cntE; i += 256) {
        int e = base + i;
        int d = dst[e];
        int b = d >> 10;
        int slot = atomicAdd(&lcur[b], 1);
        stage[slot] = ((unsigned)src[e] << 10) | (unsigned)(d & 1023);
    }
    __syncthreads();
    int total = offs[NBK];
    for (int j = threadIdx.x; j < total; j += 256) {
        int lo = 0, hi = NBK;
        while (lo < hi) { int mid = (lo + hi) >> 1; if (offs[mid + 1] <= j) lo = mid + 1; else hi = mid; }
        pairs[gbase[lo] + (j - offs[lo])] = stage[j];
    }
}

// =============== Phase B: per-bucket hist + scan -> rowptr, then scatter -> csr ===============

__global__ __launch_bounds__(256) void bucket_build(const unsigned* __restrict__ pairs,
                                                    const int* __restrict__ bbase,
                                                    int* __restrict__ rowptr,
                                                    int* __restrict__ csr, int N, int E) {
    __shared__ int cnt[BKT];
    __shared__ int psum[256];
    int b = blockIdx.x;
    int nbase = b << 10;
    int pbeg = bbase[b], pend = bbase[b + 1];
    for (int i = threadIdx.x; i < BKT; i += 256) cnt[i] = 0;
    __syncthreads();
    for (int j = pbeg + (int)threadIdx.x; j < pend; j += 256)
        atomicAdd(&cnt[pairs[j] & 1023u], 1);
    __syncthreads();
    int i0 = threadIdx.x * 4;
    int c0 = cnt[i0], c1 = cnt[i0 + 1], c2 = cnt[i0 + 2], c3 = cnt[i0 + 3];
    int local = c0 + c1 + c2 + c3;
    psum[threadIdx.x] = local;
    __syncthreads();
    for (int d = 1; d < 256; d <<= 1) {
        int t = (threadIdx.x >= d) ? psum[threadIdx.x - d] : 0;
        __syncthreads();
        psum[threadIdx.x] += t;
        __syncthreads();
    }
    int excl = psum[threadIdx.x] - local;
    int o0 = pbeg + excl;
    int o1 = o0 + c0, o2 = o1 + c1, o3 = o2 + c2;
    int n0 = nbase + i0;
    if (n0 < N)     rowptr[n0]     = o0;
    if (n0 + 1 < N) rowptr[n0 + 1] = o1;
    if (n0 + 2 < N) rowptr[n0 + 2] = o2;
    if (n0 + 3 < N) rowptr[n0 + 3] = o3;
    cnt[i0] = o0; cnt[i0 + 1] = o1; cnt[i0 + 2] = o2; cnt[i0 + 3] = o3;
    __syncthreads();
    for (int j = pbeg + (int)threadIdx.x; j < pend; j += 256) {
        unsigned p = pairs[j];
        int slot = atomicAdd(&cnt[p & 1023u], 1);
        csr[slot] = (int)(p >> 10);
    }
    if (b == 0 && threadIdx.x == 0) rowptr[N] = E;
}

// =============== K1 (MFMA): g1 = bf16( (X @ W1) * dinv ) ===============

__global__ __launch_bounds__(256) void gemm1_mfma(const float* __restrict__ X,
                                                  const float* __restrict__ W,
                                                  const int* __restrict__ rowptr,
                                                  __bf16* __restrict__ gbh, int N) {
    __shared__ __align__(16) __bf16 Wt[64][136];
    for (int i = threadIdx.x; i < 128 * 64; i += 256) {
        int k = i >> 6, c = i & 63;
        Wt[c][k] = (__bf16)W[i];
    }
    __syncthreads();

    int wave = threadIdx.x >> 6;
    int l = threadIdx.x & 63;
    int cidx = l & 15;
    int g = l >> 4;
    int wbase = blockIdx.x * 64 + wave * 16;

    int arow = wbase + cidx;
    int arowc = min(arow, N - 1);
    const float4* xr = (const float4*)(X + (size_t)arowc * 128);
    bf16x8 afr[4];
#pragma unroll
    for (int kb = 0; kb < 4; ++kb) {
        float4 p = xr[kb * 8 + g * 2];
        float4 q = xr[kb * 8 + g * 2 + 1];
        bf16x8 a;
        a[0] = (__bf16)p.x; a[1] = (__bf16)p.y; a[2] = (__bf16)p.z; a[3] = (__bf16)p.w;
        a[4] = (__bf16)q.x; a[5] = (__bf16)q.y; a[6] = (__bf16)q.z; a[7] = (__bf16)q.w;
        afr[kb] = a;
    }

    floatx4 acc[4];
#pragma unroll
    for (int ct = 0; ct < 4; ++ct) acc[ct] = (floatx4){0.f, 0.f, 0.f, 0.f};

#pragma unroll
    for (int ct = 0; ct < 4; ++ct) {
#pragma unroll
        for (int kb = 0; kb < 4; ++kb) {
            bf16x8 bfr = *(const bf16x8*)&Wt[ct * 16 + cidx][kb * 32 + g * 8];
            acc[ct] = __builtin_amdgcn_mfma_f32_16x16x32_bf16(afr[kb], bfr, acc[ct], 0, 0, 0);
        }
    }

    int r0 = wbase + g * 4;
    int rp[5];
#pragma unroll
    for (int i = 0; i < 5; ++i) rp[i] = rowptr[min(r0 + i, N)];
#pragma unroll
    for (int i = 0; i < 4; ++i) {
        int row = r0 + i;
        if (row < N) {
            float dv = rsqrtf((float)(rp[i + 1] - rp[i]) + 1.0f);
#pragma unroll
            for (int ct = 0; ct < 4; ++ct)
                gbh[(size_t)row * 64 + ct * 16 + cidx] = (__bf16)(acc[ct][i] * dv);
        }
    }
}

// =============== gather: h = bf16(relu(dinv*agg(g)+b)) — 16 lanes/node, nt index/output ===============

__global__ __launch_bounds__(256) void gather_relu_kernel(const ushort4* __restrict__ gb,
                                                          const int* __restrict__ rowptr,
                                                          const int* __restrict__ csr,
                                                          const float* __restrict__ bias,
                                                          ushort4* __restrict__ h, int N) {
    int tid = blockIdx.x * blockDim.x + threadIdx.x;
    int node = tid >> 4;
    if (node >= N) return;
    int t = tid & 15;
    int beg = rowptr[node], end = rowptr[node + 1];
    float dinv = rsqrtf((float)(end - beg) + 1.0f);
    float4 acc = bf4(gb[(size_t)node * 16 + t]);   // self-loop
    int j = beg;
    for (; j + 8 <= end; j += 8) {
        int s0 = __builtin_nontemporal_load(csr + j);
        int s1 = __builtin_nontemporal_load(csr + j + 1);
        int s2 = __builtin_nontemporal_load(csr + j + 2);
        int s3 = __builtin_nontemporal_load(csr + j + 3);
        int s4 = __builtin_nontemporal_load(csr + j + 4);
        int s5 = __builtin_nontemporal_load(csr + j + 5);
        int s6 = __builtin_nontemporal_load(csr + j + 6);
        int s7 = __builtin_nontemporal_load(csr + j + 7);
        float4 v0 = bf4(gb[(size_t)s0 * 16 + t]);
        float4 v1 = bf4(gb[(size_t)s1 * 16 + t]);
        float4 v2 = bf4(gb[(size_t)s2 * 16 + t]);
        float4 v3 = bf4(gb[(size_t)s3 * 16 + t]);
        float4 v4 = bf4(gb[(size_t)s4 * 16 + t]);
        float4 v5 = bf4(gb[(size_t)s5 * 16 + t]);
        float4 v6 = bf4(gb[(size_t)s6 * 16 + t]);
        float4 v7 = bf4(gb[(size_t)s7 * 16 + t]);
        acc.x += ((v0.x + v1.x) + (v2.x + v3.x)) + ((v4.x + v5.x) + (v6.x + v7.x));
        acc.y += ((v0.y + v1.y) + (v2.y + v3.y)) + ((v4.y + v5.y) + (v6.y + v7.y));
        acc.z += ((v0.z + v1.z) + (v2.z + v3.z)) + ((v4.z + v5.z) + (v6.z + v7.z));
        acc.w += ((v0.w + v1.w) + (v2.w + v3.w)) + ((v4.w + v5.w) + (v6.w + v7.w));
    }
    for (; j + 2 <= end; j += 2) {
        int s0 = __builtin_nontemporal_load(csr + j);
        int s1 = __builtin_nontemporal_load(csr + j + 1);
        float4 v0 = bf4(gb[(size_t)s0 * 16 + t]);
        float4 v1 = bf4(gb[(size_t)s1 * 16 + t]);
        acc.x += v0.x + v1.x; acc.y += v0.y + v1.y;
        acc.z += v0.z + v1.z; acc.w += v0.w + v1.w;
    }
    if (j < end) {
        int s0 = __builtin_nontemporal_load(csr + j);
        float4 v0 = bf4(gb[(size_t)s0 * 16 + t]);
        acc.x += v0.x; acc.y += v0.y; acc.z += v0.z; acc.w += v0.w;
    }
    float4 bb = *(const float4*)&bias[t * 4];
    unsigned lo = packpair(fmaxf(acc.x * dinv + bb.x, 0.f), fmaxf(acc.y * dinv + bb.y, 0.f));
    unsigned hi = packpair(fmaxf(acc.z * dinv + bb.z, 0.f), fmaxf(acc.w * dinv + bb.w, 0.f));
    unsigned long long packed = ((unsigned long long)hi << 32) | lo;
    __builtin_nontemporal_store(packed, (unsigned long long*)&h[(size_t)node * 16 + t]);
}

// =============== K2b (MFMA): g2 = bf16( (h @ W2) * dinv ) ===============

__global__ __launch_bounds__(256) void gemm64_mfma(const __bf16* __restrict__ H,
                                                   const float* __restrict__ W,
                                                   const int* __restrict__ rowptr,
                                                   __bf16* __restrict__ out, int N) {
    __shared__ __align__(16) __bf16 Wt[64][72];
    for (int i = threadIdx.x; i < 64 * 64; i += 256) {
        int k = i >> 6, c = i & 63;
        Wt[c][k] = (__bf16)W[i];
    }
    __syncthreads();

    int wave = threadIdx.x >> 6;
    int l = threadIdx.x & 63;
    int cidx = l & 15;
    int g = l >> 4;
    int wbase = blockIdx.x * 64 + wave * 16;

    int arow = wbase + cidx;
    int arowc = min(arow, N - 1);
    const bf16x8* hr = (const bf16x8*)(H + (size_t)arowc * 64);
    bf16x8 afr[2];
#pragma unroll
    for (int kb = 0; kb < 2; ++kb) afr[kb] = hr[kb * 4 + g];

    floatx4 acc[4];
#pragma unroll
    for (int ct = 0; ct < 4; ++ct) acc[ct] = (floatx4){0.f, 0.f, 0.f, 0.f};

#pragma unroll
    for (int ct = 0; ct < 4; ++ct) {
#pragma unroll
        for (int kb = 0; kb < 2; ++kb) {
            bf16x8 bfr = *(const bf16x8*)&Wt[ct * 16 + cidx][kb * 32 + g * 8];
            acc[ct] = __builtin_amdgcn_mfma_f32_16x16x32_bf16(afr[kb], bfr, acc[ct], 0, 0, 0);
        }
    }

    int r0 = wbase + g * 4;
    int rp[5];
#pragma unroll
    for (int i = 0; i < 5; ++i) rp[i] = rowptr[min(r0 + i, N)];
#pragma unroll
    for (int i = 0; i < 4; ++i) {
        int row = r0 + i;
        if (row < N) {
            float dv = rsqrtf((float)(rp[i + 1] - rp[i]) + 1.0f);
#pragma unroll
            for (int ct = 0; ct < 4; ++ct)
                out[(size_t)row * 64 + ct * 16 + cidx] = (__bf16)(acc[ct][i] * dv);
        }
    }
}

// =============== K3: p[n] = dinv*( relu(dinv*agg(g2)+b2) . w3l ) — 16 lanes/node ===============

__global__ __launch_bounds__(256) void agg_dot2_kernel(const ushort4* __restrict__ gb,
                                                       const int* __restrict__ rowptr,
                                                       const int* __restrict__ csr,
                                                       const float* __restrict__ bias,
                                                       const float* __restrict__ w3l,
                                                       float* __restrict__ p, int N) {
    int tid = blockIdx.x * blockDim.x + threadIdx.x;
    int node = tid >> 4;
    if (node >= N) return;
    int t = tid & 15;
    int beg = rowptr[node], end = rowptr[node + 1];
    float dinv = rsqrtf((float)(end - beg) + 1.0f);
    float4 acc = bf4(gb[(size_t)node * 16 + t]);
    int j = beg;
    for (; j + 8 <= end; j += 8) {
        int s0 = __builtin_nontemporal_load(csr + j);
        int s1 = __builtin_nontemporal_load(csr + j + 1);
        int s2 = __builtin_nontemporal_load(csr + j + 2);
        int s3 = __builtin_nontemporal_load(csr + j + 3);
        int s4 = __builtin_nontemporal_load(csr + j + 4);
        int s5 = __builtin_nontemporal_load(csr + j + 5);
        int s6 = __builtin_nontemporal_load(csr + j + 6);
        int s7 = __builtin_nontemporal_load(csr + j + 7);
        float4 v0 = bf4(gb[(size_t)s0 * 16 + t]);
        float4 v1 = bf4(gb[(size_t)s1 * 16 + t]);
        float4 v2 = bf4(gb[(size_t)s2 * 16 + t]);
        float4 v3 = bf4(gb[(size_t)s3 * 16 + t]);
        float4 v4 = bf4(gb[(size_t)s4 * 16 + t]);
        float4 v5 = bf4(gb[(size_t)s5 * 16 + t]);
        float4 v6 = bf4(gb[(size_t)s6 * 16 + t]);
        float4 v7 = bf4(gb[(size_t)s7 * 16 + t]);
        acc.x += ((v0.x + v1.x) + (v2.x + v3.x)) + ((v4.x + v5.x) + (v6.x + v7.x));
        acc.y += ((v0.y + v1.y) + (v2.y + v3.y)) + ((v4.y + v5.y) + (v6.y + v7.y));
        acc.z += ((v0.z + v1.z) + (v2.z + v3.z)) + ((v4.z + v5.z) + (v6.z + v7.z));
        acc.w += ((v0.w + v1.w) + (v2.w + v3.w)) + ((v4.w + v5.w) + (v6.w + v7.w));
    }
    for (; j + 2 <= end; j += 2) {
        int s0 = __builtin_nontemporal_load(csr + j);
        int s1 = __builtin_nontemporal_load(csr + j + 1);
        float4 v0 = bf4(gb[(size_t)s0 * 16 + t]);
        float4 v1 = bf4(gb[(size_t)s1 * 16 + t]);
        acc.x += v0.x + v1.x; acc.y += v0.y + v1.y;
        acc.z += v0.z + v1.z; acc.w += v0.w + v1.w;
    }
    if (j < end) {
        int s0 = __builtin_nontemporal_load(csr + j);
        float4 v0 = bf4(gb[(size_t)s0 * 16 + t]);
        acc.x += v0.x; acc.y += v0.y; acc.z += v0.z; acc.w += v0.w;
    }
    float4 bb = *(const float4*)&bias[t * 4];
    float4 wv = *(const float4*)&w3l[t * 4];
    float hx = fmaxf(acc.x * dinv + bb.x, 0.f);
    float hy = fmaxf(acc.y * dinv + bb.y, 0.f);
    float hz = fmaxf(acc.z * dinv + bb.z, 0.f);
    float hw = fmaxf(acc.w * dinv + bb.w, 0.f);
    float s = (hx * wv.x + hy * wv.y) + (hz * wv.z + hw * wv.w);
    s += __shfl_xor(s, 1);
    s += __shfl_xor(s, 2);
    s += __shfl_xor(s, 4);
    s += __shfl_xor(s, 8);
    if (t == 0) p[node] = s * dinv;
}

// =============== scalar aggregation ===============

__global__ __launch_bounds__(256) void scalar_agg(const float* __restrict__ p,
                                                  const int* __restrict__ rowptr,
                                                  const int* __restrict__ csr,
                                                  float* __restrict__ s_node, int N) {
    int n = blockIdx.x * 256 + threadIdx.x;
    if (n >= N) return;
    int beg = rowptr[n], end = rowptr[n + 1];
    float dinv = rsqrtf((float)(end - beg) + 1.0f);
    float acc = p[n];
    int j = beg;
    for (; j + 4 <= end; j += 4) {
        int s0 = __builtin_nontemporal_load(csr + j);
        int s1 = __builtin_nontemporal_load(csr + j + 1);
        int s2 = __builtin_nontemporal_load(csr + j + 2);
        int s3 = __builtin_nontemporal_load(csr + j + 3);
        acc += (p[s0] + p[s1]) + (p[s2] + p[s3]);
    }
    for (; j < end; ++j) acc += p[__builtin_nontemporal_load(csr + j)];
    s_node[n] = acc * dinv;
}

// =============== pool + project ===============

__device__ __forceinline__ int lower_bound_dev(const int* __restrict__ a, int n, int v) {
    int lo = 0, hi = n;
    while (lo < hi) { int mid = (lo + hi) >> 1; if (a[mid] < v) lo = mid + 1; else hi = mid; }
    return lo;
}

__global__ void pool_out_kernel(const float* __restrict__ s_node, const int* __restrict__ batch,
                                const float* __restrict__ b3, const float* __restrict__ Wl,
                                const float* __restrict__ bl, float* __restrict__ out, int N) {
    float v = b3[threadIdx.x] * Wl[threadIdx.x];
    for (int d = 32; d; d >>= 1) v += __shfl_down(v, d);
    float bldot = __shfl(v, 0, 64);

    int gidx = blockIdx.x;
    int lo = lower_bound_dev(batch, N, gidx);
    int hi = lower_bound_dev(batch, N, gidx + 1);
    float s = 0.f;
    for (int i = lo + threadIdx.x; i < hi; i += 64) s += s_node[i];
    for (int d = 32; d; d >>= 1) s += __shfl_down(s, d);
    if (threadIdx.x == 0)
        out[gidx] = s / fmaxf((float)(hi - lo), 1.0f) + bldot + bl[0];
}

// =============== launcher ===============

extern "C" void kernel_launch(void* const* d_in, const int* in_sizes, int n_in,
                              void* d_out, int out_size, void* d_ws, size_t ws_size,
                              hipStream_t stream) {
    const float* x   = (const float*)d_in[0];
    const int*   ei  = (const int*)d_in[1];
    const int*   bat = (const int*)d_in[2];
    const float* W1  = (const float*)d_in[3];
    const float* b1  = (const float*)d_in[4];
    const float* W2  = (const float*)d_in[5];
    const float* b2  = (const float*)d_in[6];
    const float* W3  = (const float*)d_in[7];
    const float* b3  = (const float*)d_in[8];
    const float* Wl  = (const float*)d_in[9];
    const float* bl  = (const float*)d_in[10];

    const int N = in_sizes[0] / 128;   // 100000
    const int E = in_sizes[1] / 2;     // 1600000
    const int G = out_size;            // 1000

    const int* src = ei;
    const int* dst = ei + E;

    const int NBK = (N + BKT - 1) / BKT;       // coarse buckets (98)
    const int Np = (N + 4) & ~3;

    // workspace layout
    int*      rowptr = (int*)d_ws;                  // Np
    int*      coarse = rowptr + Np;                 // 128
    int*      bbase  = coarse + 128;                // 132
    float*    w3l    = (float*)(bbase + 132);       // 64
    int*      gbcur  = (int*)(w3l + 64);            // NBK*16 padded cursors
    int*      csr    = gbcur + (size_t)NBK * 16;    // E
    unsigned* pairs  = (unsigned*)(csr + E);        // E (packed u32)
    ushort4*  gbA    = (ushort4*)(pairs + E);       // N*16 (bf16 features)
    ushort4*  gbB    = gbA + (size_t)N * 16;        // N*16
    ushort4*  hbuf   = gbB + (size_t)N * 16;        // N*16
    float*    pbuf   = (float*)(hbuf + (size_t)N * 16);  // N
    float*    s_node = pbuf + N;                         // N

    // ---- CSR build + w3l ----
    hipMemsetAsync(coarse, 0, (324 + (size_t)NBK * 16) * sizeof(int), stream);
    coarse_hist<<<256, 256, 0, stream>>>(dst, coarse, E, NBK);
    scan_w3l_kernel<<<1, 64, 0, stream>>>(coarse, bbase, W3, Wl, w3l, NBK, E);
    partition_kernel<<<(E + EPB - 1) / EPB, 256, 0, stream>>>(src, dst, bbase, gbcur, pairs, E, NBK);
    bucket_build<<<NBK, 256, 0, stream>>>(pairs, bbase, rowptr, csr, N, E);

    const int aggGrid = (int)(((size_t)N * 16 + 255) / 256);

    gemm1_mfma<<<(N + 63) / 64, 256, 0, stream>>>(x, W1, rowptr, (__bf16*)gbA, N);
    gather_relu_kernel<<<aggGrid, 256, 0, stream>>>(gbA, rowptr, csr, b1, hbuf, N);
    gemm64_mfma<<<(N + 63) / 64, 256, 0, stream>>>((const __bf16*)hbuf, W2, rowptr, (__bf16*)gbB, N);
    agg_dot2_kernel<<<aggGrid, 256, 0, stream>>>(gbB, rowptr, csr, b2, w3l, pbuf, N);
    scalar_agg<<<(N + 255) / 256, 256, 0, stream>>>(pbuf, rowptr, csr, s_node, N);
    pool_out_kernel<<<G, 64, 0, stream>>>(s_node, bat, b3, Wl, bl, (float*)d_out, N);
}

// Round 18
// 232.175 us; speedup vs baseline: 1.0464x; 1.0464x over previous
//
#include <hip/hip_runtime.h>
#include <stdint.h>

#define BKT 1024   // nodes per coarse bucket
#define EPB 4096   // edges per partition block

typedef __attribute__((ext_vector_type(8))) __bf16 bf16x8;
typedef __attribute__((ext_vector_type(4))) float floatx4;

// ---- bf16 helpers (RNE pack, exact expand) ----
__device__ __forceinline__ float bf2f(unsigned short h) {
    return __uint_as_float(((unsigned)h) << 16);
}
__device__ __forceinline__ float4 bf4(ushort4 v) {
    return make_float4(bf2f(v.x), bf2f(v.y), bf2f(v.z), bf2f(v.w));
}
__device__ __forceinline__ unsigned short f2bf(float f) {
    unsigned u = __float_as_uint(f);
    u = u + 0x7FFFu + ((u >> 16) & 1u);
    return (unsigned short)(u >> 16);
}
__device__ __forceinline__ ushort4 pack4(float a, float b, float c, float d) {
    ushort4 r; r.x = f2bf(a); r.y = f2bf(b); r.z = f2bf(c); r.w = f2bf(d); return r;
}

// =============== w3l = W3 . Wl (64-vector) ===============

__global__ void w3l_kernel(const float* __restrict__ W3, const float* __restrict__ Wl,
                           float* __restrict__ w3l) {
    int k = threadIdx.x;   // 64 threads
    float s = 0.f;
#pragma unroll 16
    for (int c = 0; c < 64; ++c) s += W3[k * 64 + c] * Wl[c];
    w3l[k] = s;
}

// =============== coarse (98-bin) histogram: LDS-reduced, int4 loads ===============

__global__ __launch_bounds__(256) void coarse_hist(const int* __restrict__ dst,
                                                   int* __restrict__ coarse, int E, int NBK) {
    __shared__ int h[128];
    if (threadIdx.x < 128) h[threadIdx.x] = 0;
    __syncthreads();
    int stride = gridDim.x * 256;
    int gid = blockIdx.x * 256 + threadIdx.x;
    const int4* d4 = (const int4*)dst;
    int E4 = E >> 2;
    for (int i = gid; i < E4; i += stride) {
        int4 v = d4[i];
        atomicAdd(&h[v.x >> 10], 1);
        atomicAdd(&h[v.y >> 10], 1);
        atomicAdd(&h[v.z >> 10], 1);
        atomicAdd(&h[v.w >> 10], 1);
    }
    for (int i = (E4 << 2) + gid; i < E; i += stride)
        atomicAdd(&h[dst[i] >> 10], 1);
    __syncthreads();
    if (threadIdx.x < NBK) {
        int v = h[threadIdx.x];
        if (v) atomicAdd(&coarse[threadIdx.x], v);
    }
}

__global__ void coarse_scan(const int* __restrict__ coarse, int* __restrict__ bbase,
                            int NBK, int E) {
    if (threadIdx.x == 0 && blockIdx.x == 0) {
        int run = 0;
        for (int i = 0; i < NBK; ++i) { bbase[i] = run; run += coarse[i]; }
        bbase[NBK] = E;
    }
}

// =============== Phase A: LDS-staged counting-sort partition by dst>>10 ===============

__global__ __launch_bounds__(256) void partition_kernel(const int* __restrict__ src,
                                                        const int* __restrict__ dst,
                                                        const int* __restrict__ bbase,
                                                        int* __restrict__ gbcur,
                                                        int2* __restrict__ pairs,
                                                        int E, int NBK) {
    __shared__ int2 stage[EPB];          // 32 KB
    __shared__ int  hist[128], offs[129], gbase[128], lcur[128];
    int base = blockIdx.x * EPB;
    int cntE = min(EPB, E - base);
    if (threadIdx.x < 128) hist[threadIdx.x] = 0;
    __syncthreads();
    {
        const int4* d4 = (const int4*)(dst + base);   // base is 4096-aligned
        int c4 = cntE >> 2;
        for (int i = threadIdx.x; i < c4; i += 256) {
            int4 v = d4[i];
            atomicAdd(&hist[v.x >> 10], 1);
            atomicAdd(&hist[v.y >> 10], 1);
            atomicAdd(&hist[v.z >> 10], 1);
            atomicAdd(&hist[v.w >> 10], 1);
        }
        for (int i = (c4 << 2) + (int)threadIdx.x; i < cntE; i += 256)
            atomicAdd(&hist[dst[base + i] >> 10], 1);
    }
    __syncthreads();
    if (threadIdx.x == 0) {
        int run = 0;
        for (int b = 0; b < NBK; ++b) { offs[b] = run; run += hist[b]; }
        offs[NBK] = run;
    }
    __syncthreads();
    if (threadIdx.x < NBK) {
        int b = threadIdx.x;
        int h = hist[b];
        if (h > 0) gbase[b] = bbase[b] + atomicAdd(&gbcur[b << 4], h);
        lcur[b] = offs[b];
    }
    __syncthreads();
    for (int i = threadIdx.x; i < cntE; i += 256) {
        int e = base + i;
        int d = dst[e];
        int b = d >> 10;
        int slot = atomicAdd(&lcur[b], 1);
        stage[slot] = make_int2(src[e], d);
    }
    __syncthreads();
    int total = offs[NBK];
    for (int j = threadIdx.x; j < total; j += 256) {
        int lo = 0, hi = NBK;
        while (lo < hi) { int mid = (lo + hi) >> 1; if (offs[mid + 1] <= j) lo = mid + 1; else hi = mid; }
        pairs[gbase[lo] + (j - offs[lo])] = stage[j];
    }
}

// =============== Phase B: per-bucket hist + scan -> rowptr, then scatter -> csr ===============

__global__ __launch_bounds__(256) void bucket_build(const int2* __restrict__ pairs,
                                                    const int* __restrict__ bbase,
                                                    int* __restrict__ rowptr,
                                                    int* __restrict__ csr, int N, int E) {
    __shared__ int cnt[BKT];      // counters -> cursors
    __shared__ int psum[256];
    int b = blockIdx.x;
    int nbase = b << 10;
    int pbeg = bbase[b], pend = bbase[b + 1];
    for (int i = threadIdx.x; i < BKT; i += 256) cnt[i] = 0;
    __syncthreads();
    for (int j = pbeg + (int)threadIdx.x; j < pend; j += 256)
        atomicAdd(&cnt[pairs[j].y - nbase], 1);
    __syncthreads();
    int i0 = threadIdx.x * 4;
    int c0 = cnt[i0], c1 = cnt[i0 + 1], c2 = cnt[i0 + 2], c3 = cnt[i0 + 3];
    int local = c0 + c1 + c2 + c3;
    psum[threadIdx.x] = local;
    __syncthreads();
    for (int d = 1; d < 256; d <<= 1) {
        int t = (threadIdx.x >= d) ? psum[threadIdx.x - d] : 0;
        __syncthreads();
        psum[threadIdx.x] += t;
        __syncthreads();
    }
    int excl = psum[threadIdx.x] - local;
    int o0 = pbeg + excl;
    int o1 = o0 + c0, o2 = o1 + c1, o3 = o2 + c2;
    int n0 = nbase + i0;
    if (n0 < N)     rowptr[n0]     = o0;
    if (n0 + 1 < N) rowptr[n0 + 1] = o1;
    if (n0 + 2 < N) rowptr[n0 + 2] = o2;
    if (n0 + 3 < N) rowptr[n0 + 3] = o3;
    cnt[i0] = o0; cnt[i0 + 1] = o1; cnt[i0 + 2] = o2; cnt[i0 + 3] = o3;
    __syncthreads();
    for (int j = pbeg + (int)threadIdx.x; j < pend; j += 256) {
        int2 p = pairs[j];
        int slot = atomicAdd(&cnt[p.y - nbase], 1);
        csr[slot] = p.x;
    }
    if (b == 0 && threadIdx.x == 0) rowptr[N] = E;
}

// =============== K1 (MFMA): g1 = bf16( (X[N,128] @ W1[128,64]) * dinv ) ===============

__global__ __launch_bounds__(256) void gemm1_mfma(const float* __restrict__ X,
                                                  const float* __restrict__ W,
                                                  const int* __restrict__ rowptr,
                                                  __bf16* __restrict__ gbh, int N) {
    __shared__ __align__(16) __bf16 Wt[64][136];
    for (int i = threadIdx.x; i < 128 * 64; i += 256) {
        int k = i >> 6, c = i & 63;
        Wt[c][k] = (__bf16)W[i];
    }
    __syncthreads();

    int wave = threadIdx.x >> 6;
    int l = threadIdx.x & 63;
    int cidx = l & 15;
    int g = l >> 4;
    int wbase = blockIdx.x * 64 + wave * 16;

    int arow = wbase + cidx;
    int arowc = min(arow, N - 1);
    const float4* xr = (const float4*)(X + (size_t)arowc * 128);
    bf16x8 afr[4];
#pragma unroll
    for (int kb = 0; kb < 4; ++kb) {
        float4 p = xr[kb * 8 + g * 2];
        float4 q = xr[kb * 8 + g * 2 + 1];
        bf16x8 a;
        a[0] = (__bf16)p.x; a[1] = (__bf16)p.y; a[2] = (__bf16)p.z; a[3] = (__bf16)p.w;
        a[4] = (__bf16)q.x; a[5] = (__bf16)q.y; a[6] = (__bf16)q.z; a[7] = (__bf16)q.w;
        afr[kb] = a;
    }

    floatx4 acc[4];
#pragma unroll
    for (int ct = 0; ct < 4; ++ct) acc[ct] = (floatx4){0.f, 0.f, 0.f, 0.f};

#pragma unroll
    for (int ct = 0; ct < 4; ++ct) {
#pragma unroll
        for (int kb = 0; kb < 4; ++kb) {
            bf16x8 bfr = *(const bf16x8*)&Wt[ct * 16 + cidx][kb * 32 + g * 8];
            acc[ct] = __builtin_amdgcn_mfma_f32_16x16x32_bf16(afr[kb], bfr, acc[ct], 0, 0, 0);
        }
    }

    int r0 = wbase + g * 4;
    int rp[5];
#pragma unroll
    for (int i = 0; i < 5; ++i) rp[i] = rowptr[min(r0 + i, N)];
#pragma unroll
    for (int i = 0; i < 4; ++i) {
        int row = r0 + i;
        if (row < N) {
            float dv = rsqrtf((float)(rp[i + 1] - rp[i]) + 1.0f);
#pragma unroll
            for (int ct = 0; ct < 4; ++ct)
                gbh[(size_t)row * 64 + ct * 16 + cidx] = (__bf16)(acc[ct][i] * dv);
        }
    }
}

// =============== fused: h = relu(dinv*agg(g) + b); out = bf16((h @ W) * dinv) ===============

__global__ __launch_bounds__(256) void fused_layer_kernel(const ushort4* __restrict__ gb,
                                                          const int* __restrict__ rowptr,
                                                          const int* __restrict__ csr,
                                                          const float* __restrict__ bias,
                                                          const float* __restrict__ W,
                                                          ushort4* __restrict__ out, int N) {
    __shared__ float Ws[64 * 64];    // 16 KB
    __shared__ float T[16][72];
    {
        const float4* Wv = (const float4*)W;
        float4* Wsv = (float4*)Ws;
        for (int i = threadIdx.x; i < 64 * 16; i += 256) Wsv[i] = Wv[i];
    }
    int row = threadIdx.x >> 4;
    int node = blockIdx.x * 16 + row;
    int t = threadIdx.x & 15;
    int c = t * 4;
    float dinv = 0.f;
    if (node < N) {
        int beg = rowptr[node], end = rowptr[node + 1];
        dinv = rsqrtf((float)(end - beg) + 1.0f);
        float4 acc = bf4(gb[(size_t)node * 16 + t]);   // self-loop
        int j = beg;
        for (; j + 8 <= end; j += 8) {
            int s0 = csr[j], s1 = csr[j + 1], s2 = csr[j + 2], s3 = csr[j + 3];
            int s4 = csr[j + 4], s5 = csr[j + 5], s6 = csr[j + 6], s7 = csr[j + 7];
            float4 v0 = bf4(gb[(size_t)s0 * 16 + t]);
            float4 v1 = bf4(gb[(size_t)s1 * 16 + t]);
            float4 v2 = bf4(gb[(size_t)s2 * 16 + t]);
            float4 v3 = bf4(gb[(size_t)s3 * 16 + t]);
            float4 v4 = bf4(gb[(size_t)s4 * 16 + t]);
            float4 v5 = bf4(gb[(size_t)s5 * 16 + t]);
            float4 v6 = bf4(gb[(size_t)s6 * 16 + t]);
            float4 v7 = bf4(gb[(size_t)s7 * 16 + t]);
            acc.x += ((v0.x + v1.x) + (v2.x + v3.x)) + ((v4.x + v5.x) + (v6.x + v7.x));
            acc.y += ((v0.y + v1.y) + (v2.y + v3.y)) + ((v4.y + v5.y) + (v6.y + v7.y));
            acc.z += ((v0.z + v1.z) + (v2.z + v3.z)) + ((v4.z + v5.z) + (v6.z + v7.z));
            acc.w += ((v0.w + v1.w) + (v2.w + v3.w)) + ((v4.w + v5.w) + (v6.w + v7.w));
        }
        for (; j + 2 <= end; j += 2) {
            int s0 = csr[j], s1 = csr[j + 1];
            float4 v0 = bf4(gb[(size_t)s0 * 16 + t]);
            float4 v1 = bf4(gb[(size_t)s1 * 16 + t]);
            acc.x += v0.x + v1.x; acc.y += v0.y + v1.y;
            acc.z += v0.z + v1.z; acc.w += v0.w + v1.w;
        }
        if (j < end) {
            int s0 = csr[j];
            float4 v0 = bf4(gb[(size_t)s0 * 16 + t]);
            acc.x += v0.x; acc.y += v0.y; acc.z += v0.z; acc.w += v0.w;
        }
        float4 bb = *(const float4*)&bias[c];
        T[row][c + 0] = fmaxf(acc.x * dinv + bb.x, 0.f);
        T[row][c + 1] = fmaxf(acc.y * dinv + bb.y, 0.f);
        T[row][c + 2] = fmaxf(acc.z * dinv + bb.z, 0.f);
        T[row][c + 3] = fmaxf(acc.w * dinv + bb.w, 0.f);
    }
    __syncthreads();
    if (node >= N) return;
    float4 o = make_float4(0.f, 0.f, 0.f, 0.f);
#pragma unroll 16
    for (int k = 0; k < 64; ++k) {
        float tv = T[row][k];
        float4 wv = *(const float4*)&Ws[k * 64 + c];
        o.x += tv * wv.x; o.y += tv * wv.y;
        o.z += tv * wv.z; o.w += tv * wv.w;
    }
    out[(size_t)node * 16 + t] = pack4(o.x * dinv, o.y * dinv, o.z * dinv, o.w * dinv);
}

// =============== K3: p[n] = dinv * ( relu(dinv*agg(g2)+b2) . w3l ) ===============

__global__ __launch_bounds__(256) void agg_dot2_kernel(const ushort4* __restrict__ gb,
                                                       const int* __restrict__ rowptr,
                                                       const int* __restrict__ csr,
                                                       const float* __restrict__ bias,
                                                       const float* __restrict__ w3l,
                                                       float* __restrict__ p, int N) {
    int tid = blockIdx.x * blockDim.x + threadIdx.x;
    int node = tid >> 4;
    if (node >= N) return;
    int t = tid & 15;
    int beg = rowptr[node], end = rowptr[node + 1];
    float dinv = rsqrtf((float)(end - beg) + 1.0f);
    float4 acc = bf4(gb[(size_t)node * 16 + t]);
    int j = beg;
    for (; j + 8 <= end; j += 8) {
        int s0 = csr[j], s1 = csr[j + 1], s2 = csr[j + 2], s3 = csr[j + 3];
        int s4 = csr[j + 4], s5 = csr[j + 5], s6 = csr[j + 6], s7 = csr[j + 7];
        float4 v0 = bf4(gb[(size_t)s0 * 16 + t]);
        float4 v1 = bf4(gb[(size_t)s1 * 16 + t]);
        float4 v2 = bf4(gb[(size_t)s2 * 16 + t]);
        float4 v3 = bf4(gb[(size_t)s3 * 16 + t]);
        float4 v4 = bf4(gb[(size_t)s4 * 16 + t]);
        float4 v5 = bf4(gb[(size_t)s5 * 16 + t]);
        float4 v6 = bf4(gb[(size_t)s6 * 16 + t]);
        float4 v7 = bf4(gb[(size_t)s7 * 16 + t]);
        acc.x += ((v0.x + v1.x) + (v2.x + v3.x)) + ((v4.x + v5.x) + (v6.x + v7.x));
        acc.y += ((v0.y + v1.y) + (v2.y + v3.y)) + ((v4.y + v5.y) + (v6.y + v7.y));
        acc.z += ((v0.z + v1.z) + (v2.z + v3.z)) + ((v4.z + v5.z) + (v6.z + v7.z));
        acc.w += ((v0.w + v1.w) + (v2.w + v3.w)) + ((v4.w + v5.w) + (v6.w + v7.w));
    }
    for (; j + 2 <= end; j += 2) {
        int s0 = csr[j], s1 = csr[j + 1];
        float4 v0 = bf4(gb[(size_t)s0 * 16 + t]);
        float4 v1 = bf4(gb[(size_t)s1 * 16 + t]);
        acc.x += v0.x + v1.x; acc.y += v0.y + v1.y;
        acc.z += v0.z + v1.z; acc.w += v0.w + v1.w;
    }
    if (j < end) {
        int s0 = csr[j];
        float4 v0 = bf4(gb[(size_t)s0 * 16 + t]);
        acc.x += v0.x; acc.y += v0.y; acc.z += v0.z; acc.w += v0.w;
    }
    float4 bb = *(const float4*)&bias[t * 4];
    float4 wv = *(const float4*)&w3l[t * 4];
    float hx = fmaxf(acc.x * dinv + bb.x, 0.f);
    float hy = fmaxf(acc.y * dinv + bb.y, 0.f);
    float hz = fmaxf(acc.z * dinv + bb.z, 0.f);
    float hw = fmaxf(acc.w * dinv + bb.w, 0.f);
    float s = (hx * wv.x + hy * wv.y) + (hz * wv.z + hw * wv.w);
    s += __shfl_xor(s, 1);
    s += __shfl_xor(s, 2);
    s += __shfl_xor(s, 4);
    s += __shfl_xor(s, 8);
    if (t == 0) p[node] = s * dinv;
}

// =============== scalar aggregation: s_node[n] = dinv_n * (p[n] + sum p[csr]) ===============

__global__ __launch_bounds__(256) void scalar_agg(const float* __restrict__ p,
                                                  const int* __restrict__ rowptr,
                                                  const int* __restrict__ csr,
                                                  float* __restrict__ s_node, int N) {
    int n = blockIdx.x * 256 + threadIdx.x;
    if (n >= N) return;
    int beg = rowptr[n], end = rowptr[n + 1];
    float dinv = rsqrtf((float)(end - beg) + 1.0f);
    float acc = p[n];
    int j = beg;
    for (; j + 4 <= end; j += 4) {
        float a0 = p[csr[j]], a1 = p[csr[j + 1]], a2 = p[csr[j + 2]], a3 = p[csr[j + 3]];
        acc += (a0 + a1) + (a2 + a3);
    }
    for (; j < end; ++j) acc += p[csr[j]];
    s_node[n] = acc * dinv;
}

// =============== K5: per-graph mean over sorted batch + (b3.Wl) + bl ===============

__device__ __forceinline__ int lower_bound_dev(const int* __restrict__ a, int n, int v) {
    int lo = 0, hi = n;
    while (lo < hi) { int mid = (lo + hi) >> 1; if (a[mid] < v) lo = mid + 1; else hi = mid; }
    return lo;
}

__global__ void pool_out_kernel(const float* __restrict__ s_node, const int* __restrict__ batch,
                                const float* __restrict__ b3, const float* __restrict__ Wl,
                                const float* __restrict__ bl, float* __restrict__ out, int N) {
    float v = b3[threadIdx.x] * Wl[threadIdx.x];
    for (int d = 32; d; d >>= 1) v += __shfl_down(v, d);
    float bldot = __shfl(v, 0, 64);

    int gidx = blockIdx.x;
    int lo = lower_bound_dev(batch, N, gidx);
    int hi = lower_bound_dev(batch, N, gidx + 1);
    float s = 0.f;
    for (int i = lo + threadIdx.x; i < hi; i += 64) s += s_node[i];
    for (int d = 32; d; d >>= 1) s += __shfl_down(s, d);
    if (threadIdx.x == 0)
        out[gidx] = s / fmaxf((float)(hi - lo), 1.0f) + bldot + bl[0];
}

// =============== launcher ===============

extern "C" void kernel_launch(void* const* d_in, const int* in_sizes, int n_in,
                              void* d_out, int out_size, void* d_ws, size_t ws_size,
                              hipStream_t stream) {
    const float* x   = (const float*)d_in[0];
    const int*   ei  = (const int*)d_in[1];
    const int*   bat = (const int*)d_in[2];
    const float* W1  = (const float*)d_in[3];
    const float* b1  = (const float*)d_in[4];
    const float* W2  = (const float*)d_in[5];
    const float* b2  = (const float*)d_in[6];
    const float* W3  = (const float*)d_in[7];
    const float* b3  = (const float*)d_in[8];
    const float* Wl  = (const float*)d_in[9];
    const float* bl  = (const float*)d_in[10];

    const int N = in_sizes[0] / 128;   // 100000
    const int E = in_sizes[1] / 2;     // 1600000
    const int G = out_size;            // 1000

    const int* src = ei;
    const int* dst = ei + E;

    const int NBK = (N + BKT - 1) / BKT;       // coarse buckets (98)
    const int Np = (N + 4) & ~3;

    // workspace layout
    int*     rowptr = (int*)d_ws;                  // Np
    int*     coarse = rowptr + Np;                 // 128
    int*     bbase  = coarse + 128;                // 132 (NBK+1, padded)
    float*   w3l    = (float*)(bbase + 132);       // 64
    int*     gbcur  = (int*)(w3l + 64);            // NBK*16 padded cursors
    int*     csr    = gbcur + (size_t)NBK * 16;    // E
    int2*    pairs  = (int2*)(csr + E);            // E
    ushort4* gbA    = (ushort4*)(pairs + E);       // N*16 (bf16 features)
    ushort4* gbB    = gbA + (size_t)N * 16;        // N*16
    float*   pbuf   = (float*)(gbB + (size_t)N * 16);  // N
    float*   s_node = pbuf + N;                        // N

    // ---- CSR build + w3l ----
    hipMemsetAsync(coarse, 0, (324 + (size_t)NBK * 16) * sizeof(int), stream);
    w3l_kernel<<<1, 64, 0, stream>>>(W3, Wl, w3l);
    coarse_hist<<<256, 256, 0, stream>>>(dst, coarse, E, NBK);
    coarse_scan<<<1, 64, 0, stream>>>(coarse, bbase, NBK, E);
    partition_kernel<<<(E + EPB - 1) / EPB, 256, 0, stream>>>(src, dst, bbase, gbcur, pairs, E, NBK);
    bucket_build<<<NBK, 256, 0, stream>>>(pairs, bbase, rowptr, csr, N, E);

    const int tileGrid = (N + 15) / 16;
    const int aggGrid  = (int)(((size_t)N * 16 + 255) / 256);

    gemm1_mfma<<<(N + 63) / 64, 256, 0, stream>>>(x, W1, rowptr, (__bf16*)gbA, N);
    fused_layer_kernel<<<tileGrid, 256, 0, stream>>>(gbA, rowptr, csr, b1, W2, gbB, N);
    agg_dot2_kernel<<<aggGrid, 256, 0, stream>>>(gbB, rowptr, csr, b2, w3l, pbuf, N);
    scalar_agg<<<(N + 255) / 256, 256, 0, stream>>>(pbuf, rowptr, csr, s_node, N);
    pool_out_kernel<<<G, 64, 0, stream>>>(s_node, bat, b3, Wl, bl, (float*)d_out, N);
}